// Round 8
// baseline (632.992 us; speedup 1.0000x reference)
//
#include <hip/hip_runtime.h>

typedef __attribute__((ext_vector_type(8))) short bf16x8;
typedef __attribute__((ext_vector_type(4))) float f32x4;

__device__ __forceinline__ unsigned short f2bf(float f){
  unsigned int u = __builtin_bit_cast(unsigned int, f);
  u += 0x7fffu + ((u >> 16) & 1u);          // RTN-even
  return (unsigned short)(u >> 16);
}
__device__ __forceinline__ unsigned int pack2(float a, float b){
  return (unsigned int)f2bf(a) | ((unsigned int)f2bf(b) << 16);
}
__device__ __forceinline__ float bf_lo(unsigned int v){
  return __builtin_bit_cast(float, v << 16);
}
__device__ __forceinline__ float bf_hi(unsigned int v){
  return __builtin_bit_cast(float, v & 0xffff0000u);
}
__device__ __forceinline__ float lrelu(float x){ return x > 0.f ? x : 0.2f * x; }

#define GLOAD_LDS16(g, l) \
  __builtin_amdgcn_global_load_lds((const __attribute__((address_space(1))) unsigned int*)(g), \
                                   (__attribute__((address_space(3))) unsigned int*)(l), 16, 0, 0)

// ------- Kernel I: zero deg + WbfT (bf16 W^T padded) + WS/WD (= W @ att^T) ---
__global__ __launch_bounds__(256) void k_init(const float* __restrict__ W,
    const float* __restrict__ attS, const float* __restrict__ attD,
    unsigned short* __restrict__ WbfT, float* __restrict__ WS, float* __restrict__ WD,
    int4* __restrict__ deg4, int n4){
  int i = blockIdx.x * 256 + threadIdx.x;
  if (i < n4){ int4 z; z.x=0; z.y=0; z.z=0; z.w=0; deg4[i] = z; }
  if (i < 128*128){
    int c = i & 127, k = i >> 7;
    WbfT[c * 136 + k] = f2bf(W[k * 128 + c]);
  }
  if (i < 512){
    int k = i >> 2, h = i & 3;
    const float* wp = W + k * 128 + h * 32;
    const float* as = attS + h * 32;
    const float* ad = attD + h * 32;
    float s = 0.f, d = 0.f;
    #pragma unroll
    for (int c = 0; c < 32; ++c){ float w = wp[c]; s += w * as[c]; d += w * ad[c]; }
    WS[k * 4 + h] = s;
    WD[k * 4 + h] = d;
  }
}

// ------- Kernel B: stream x -> bf16 xb, fused aS = x@WS, aD = x@WD -----------
// 16 lanes per row, 8 ch/lane. Pure streaming, no LDS, no MFMA.
__global__ __launch_bounds__(256) void k_cast(
    const float* __restrict__ x, const float* __restrict__ WS,
    const float* __restrict__ WD, uint4* __restrict__ xb4,
    float* __restrict__ aS, float* __restrict__ aD, int N)
{
  int tid = threadIdx.x;
  int row = blockIdx.x * 16 + (tid >> 4);
  int l16 = tid & 15;
  if (row >= N) return;
  const f32x4* xp = (const f32x4*)(x + (size_t)row * 128 + l16 * 8);
  f32x4 v0 = xp[0], v1 = xp[1];
  const f32x4* WS4 = (const f32x4*)WS;
  const f32x4* WD4 = (const f32x4*)WD;
  int c0 = l16 * 8;
  f32x4 ps = WS4[c0] * v0[0];
  f32x4 pd = WD4[c0] * v0[0];
  #pragma unroll
  for (int j = 1; j < 4; ++j){ ps += WS4[c0+j] * v0[j]; pd += WD4[c0+j] * v0[j]; }
  #pragma unroll
  for (int j = 0; j < 4; ++j){ ps += WS4[c0+4+j] * v1[j]; pd += WD4[c0+4+j] * v1[j]; }
  #pragma unroll
  for (int m = 1; m < 16; m <<= 1){
    #pragma unroll
    for (int g = 0; g < 4; ++g){
      ps[g] += __shfl_xor(ps[g], m, 64);
      pd[g] += __shfl_xor(pd[g], m, 64);
    }
  }
  uint4 u;
  u.x = pack2(v0[0], v0[1]);  u.y = pack2(v0[2], v0[3]);
  u.z = pack2(v1[0], v1[1]);  u.w = pack2(v1[2], v1[3]);
  xb4[(size_t)row * 16 + l16] = u;
  if (l16 == 0){
    *(f32x4*)(aS + (size_t)row * 4) = ps;
    *(f32x4*)(aD + (size_t)row * 4) = pd;
  }
}

// ---------------- CSR build ----------------
__global__ __launch_bounds__(256) void k_hist(const int* __restrict__ dst, int E,
                                              int* __restrict__ deg){
  int e = blockIdx.x * 256 + threadIdx.x;
  if (e < E) atomicAdd(&deg[dst[e]], 1);
}

__global__ __launch_bounds__(256) void k_chunksum(const int* __restrict__ deg, int N,
                                                  int* __restrict__ bsum){
  __shared__ int sm[256];
  int tid = threadIdx.x;
  int base = blockIdx.x * 2048 + tid * 8;
  int s = 0;
  #pragma unroll
  for (int j = 0; j < 8; ++j) s += (base + j < N) ? deg[base + j] : 0;
  sm[tid] = s; __syncthreads();
  for (int off = 128; off > 0; off >>= 1){
    if (tid < off) sm[tid] += sm[tid + off];
    __syncthreads();
  }
  if (tid == 0) bsum[blockIdx.x] = sm[0];
}

__global__ __launch_bounds__(256) void k_scansums(int* __restrict__ bsum, int nb){
  __shared__ int sm[256];
  int tid = threadIdx.x;
  int carry = 0;
  for (int base = 0; base < nb; base += 256){
    int v = (base + tid < nb) ? bsum[base + tid] : 0;
    sm[tid] = v; __syncthreads();
    for (int off = 1; off < 256; off <<= 1){
      int t = (tid >= off) ? sm[tid - off] : 0;
      __syncthreads();
      sm[tid] += t;
      __syncthreads();
    }
    int incl = sm[tid];
    int total = sm[255];
    __syncthreads();
    if (base + tid < nb) bsum[base + tid] = carry + incl - v;
    carry += total;
  }
}

__global__ __launch_bounds__(256) void k_scanfinal(const int* __restrict__ deg,
    const int* __restrict__ bsum, int N, int E,
    int* __restrict__ rowptr, int* __restrict__ cursor){
  __shared__ int sm[256];
  int tid = threadIdx.x;
  int base = blockIdx.x * 2048 + tid * 8;
  int v[8];
  #pragma unroll
  for (int j = 0; j < 8; ++j) v[j] = (base + j < N) ? deg[base + j] : 0;
  int t = 0;
  #pragma unroll
  for (int j = 0; j < 8; ++j){ int x_ = v[j]; v[j] = t; t += x_; }
  sm[tid] = t; __syncthreads();
  for (int off = 1; off < 256; off <<= 1){
    int u = (tid >= off) ? sm[tid - off] : 0;
    __syncthreads();
    sm[tid] += u;
    __syncthreads();
  }
  int excl = sm[tid] - t;
  int off0 = bsum[blockIdx.x] + excl;
  #pragma unroll
  for (int j = 0; j < 8; ++j){
    if (base + j < N){
      int val = off0 + v[j];
      rowptr[base + j] = val;
      cursor[base + j] = val;
    }
  }
  if (blockIdx.x == 0 && tid == 0) rowptr[N] = E;
}

__global__ __launch_bounds__(256) void k_scatter(const int* __restrict__ src,
    const int* __restrict__ dst, int E, int* __restrict__ cursor,
    int* __restrict__ csr){
  int e = blockIdx.x * 256 + threadIdx.x;
  if (e < E){
    int d = dst[e];
    int p = atomicAdd(&cursor[d], 1);
    csr[p] = src[e];
  }
}

// ------- Kernel C: fused gather + per-head aggregate + MFMA matvec + head ----
// Wave batch = 4 nodes. Gather phase: 16 lanes/node, lane owns 8 k-channels,
// accumulates xagg[h][8] for ALL 4 heads (weights broadcast via shfl).
// Then: bf16 rows -> wave-private LDS tile (16 rows = (node,head) slots),
// B-frags read back, 32 MFMAs vs W^T (LDS), fused bias/relu/fc/sigmoid.
__global__ __launch_bounds__(256) void k_aggr2(
    const uint4* __restrict__ xb4, const float* __restrict__ aS,
    const float* __restrict__ aD, const int* __restrict__ rowptr,
    const int* __restrict__ csr, const float* __restrict__ bias,
    const float* __restrict__ fcw, const float* __restrict__ fcb,
    const unsigned short* __restrict__ WbfT, float* __restrict__ out,
    int N, int nbatch)
{
  __shared__ alignas(16) unsigned short Wt[128][136];   // 34816 B
  __shared__ alignas(16) unsigned short Xt[4][16][136]; // 17408 B (padded rows)
  int tid = threadIdx.x;

  const char* wsrc = (const char*)WbfT;
  #pragma unroll
  for (int it = 0; it < 9; ++it){
    int i = it * 256 + tid;
    if (i < 2176) GLOAD_LDS16(wsrc + (size_t)i * 16, ((char*)Wt) + i * 16);
  }
  __syncthreads();

  int wv = tid >> 6, lane = tid & 63;
  int l16 = lane & 15, g4 = lane >> 4;    // g4: node-in-batch (gather) / lgrp (mfma)
  int head = l16 >> 2;
  int lb = lane & 48;

  for (int bt = (int)blockIdx.x * 4 + wv; bt < nbatch; bt += (int)gridDim.x * 4){
    int node = bt * 4 + g4;
    bool valid = node < N;
    int nc = valid ? node : N - 1;

    float ad    = aD[nc * 4 + head];
    float wown  = __expf(lrelu(aS[nc * 4 + head] + ad));
    float wsum  = wown;
    float wh0 = __shfl(wown, lb,      64);
    float wh1 = __shfl(wown, lb +  4, 64);
    float wh2 = __shfl(wown, lb +  8, 64);
    float wh3 = __shfl(wown, lb + 12, 64);

    f32x4 xa0l, xa0h, xa1l, xa1h, xa2l, xa2h, xa3l, xa3h;
    {
      uint4 v = xb4[(size_t)nc * 16 + l16];
      f32x4 vl; vl[0]=bf_lo(v.x); vl[1]=bf_hi(v.x); vl[2]=bf_lo(v.y); vl[3]=bf_hi(v.y);
      f32x4 vh; vh[0]=bf_lo(v.z); vh[1]=bf_hi(v.z); vh[2]=bf_lo(v.w); vh[3]=bf_hi(v.w);
      xa0l = vl * wh0; xa0h = vh * wh0;
      xa1l = vl * wh1; xa1h = vh * wh1;
      xa2l = vl * wh2; xa2h = vh * wh2;
      xa3l = vl * wh3; xa3h = vh * wh3;
    }

    int rb = valid ? rowptr[node] : 0;
    int re = valid ? rowptr[node + 1] : 0;
    for (int j = rb; j < re; j += 2){
      int i1 = (j + 1 < re) ? j + 1 : j;
      int s0 = csr[j], s1 = csr[i1];
      float m1 = (j + 1 < re) ? 1.f : 0.f;
      float a0 = aS[s0 * 4 + head];
      float a1 = aS[s1 * 4 + head];
      uint4 v0 = xb4[(size_t)s0 * 16 + l16];
      uint4 v1 = xb4[(size_t)s1 * 16 + l16];
      float w0 = __expf(lrelu(a0 + ad));
      float w1 = __expf(lrelu(a1 + ad)) * m1;
      wsum += w0 + w1;
      float e0h0 = __shfl(w0, lb, 64),    e0h1 = __shfl(w0, lb+4, 64);
      float e0h2 = __shfl(w0, lb+8, 64),  e0h3 = __shfl(w0, lb+12, 64);
      float e1h0 = __shfl(w1, lb, 64),    e1h1 = __shfl(w1, lb+4, 64);
      float e1h2 = __shfl(w1, lb+8, 64),  e1h3 = __shfl(w1, lb+12, 64);
      f32x4 v0l; v0l[0]=bf_lo(v0.x); v0l[1]=bf_hi(v0.x); v0l[2]=bf_lo(v0.y); v0l[3]=bf_hi(v0.y);
      f32x4 v0h; v0h[0]=bf_lo(v0.z); v0h[1]=bf_hi(v0.z); v0h[2]=bf_lo(v0.w); v0h[3]=bf_hi(v0.w);
      f32x4 v1l; v1l[0]=bf_lo(v1.x); v1l[1]=bf_hi(v1.x); v1l[2]=bf_lo(v1.y); v1l[3]=bf_hi(v1.y);
      f32x4 v1h; v1h[0]=bf_lo(v1.z); v1h[1]=bf_hi(v1.z); v1h[2]=bf_lo(v1.w); v1h[3]=bf_hi(v1.w);
      xa0l += v0l * e0h0 + v1l * e1h0;  xa0h += v0h * e0h0 + v1h * e1h0;
      xa1l += v0l * e0h1 + v1l * e1h1;  xa1h += v0h * e0h1 + v1h * e1h1;
      xa2l += v0l * e0h2 + v1l * e1h2;  xa2h += v0h * e0h2 + v1h * e1h2;
      xa3l += v0l * e0h3 + v1l * e1h3;  xa3h += v0h * e0h3 + v1h * e1h3;
    }

    // ---- deposit bf16 rows into wave-private LDS tile: row = node*4 + h ----
    asm volatile("s_waitcnt lgkmcnt(0)" ::: "memory");  // prev iter's reads done
    __builtin_amdgcn_sched_barrier(0);
    {
      uint4 u;
      u.x = pack2(xa0l[0], xa0l[1]); u.y = pack2(xa0l[2], xa0l[3]);
      u.z = pack2(xa0h[0], xa0h[1]); u.w = pack2(xa0h[2], xa0h[3]);
      *(uint4*)&Xt[wv][g4*4 + 0][l16*8] = u;
      u.x = pack2(xa1l[0], xa1l[1]); u.y = pack2(xa1l[2], xa1l[3]);
      u.z = pack2(xa1h[0], xa1h[1]); u.w = pack2(xa1h[2], xa1h[3]);
      *(uint4*)&Xt[wv][g4*4 + 1][l16*8] = u;
      u.x = pack2(xa2l[0], xa2l[1]); u.y = pack2(xa2l[2], xa2l[3]);
      u.z = pack2(xa2h[0], xa2h[1]); u.w = pack2(xa2h[2], xa2h[3]);
      *(uint4*)&Xt[wv][g4*4 + 2][l16*8] = u;
      u.x = pack2(xa3l[0], xa3l[1]); u.y = pack2(xa3l[2], xa3l[3]);
      u.z = pack2(xa3h[0], xa3h[1]); u.w = pack2(xa3h[2], xa3h[3]);
      *(uint4*)&Xt[wv][g4*4 + 3][l16*8] = u;
    }
    asm volatile("s_waitcnt lgkmcnt(0)" ::: "memory");  // writes visible to wave
    __builtin_amdgcn_sched_barrier(0);

    // ---- B-frags + MFMA sweep ----
    bf16x8 bfrag[4];
    #pragma unroll
    for (int kt = 0; kt < 4; ++kt)
      bfrag[kt] = *(const bf16x8*)&Xt[wv][l16][kt*32 + g4*8];

    f32x4 acc[8];
    #pragma unroll
    for (int ct = 0; ct < 8; ++ct){ acc[ct][0]=0.f; acc[ct][1]=0.f; acc[ct][2]=0.f; acc[ct][3]=0.f; }
    #pragma unroll
    for (int kt = 0; kt < 4; ++kt){
      #pragma unroll
      for (int ct = 0; ct < 8; ++ct){
        bf16x8 aw = *(const bf16x8*)&Wt[ct*16 + l16][kt*32 + g4*8];
        acc[ct] = __builtin_amdgcn_mfma_f32_16x16x32_bf16(aw, bfrag[kt], acc[ct], 0, 0, 0);
      }
    }

    // ---- epilogue: lane col = l16 = slot (n2,hh); chs = hh*32 + g4*4 (+16) --
    int n2 = l16 >> 2, hh = l16 & 3;
    float wsumh = __shfl(wsum, (n2 << 4) + (hh << 2), 64);
    float inv = 1.f / wsumh;
    f32x4 aA = (hh==0)?acc[0]:((hh==1)?acc[2]:((hh==2)?acc[4]:acc[6]));
    f32x4 aB = (hh==0)?acc[1]:((hh==1)?acc[3]:((hh==2)?acc[5]:acc[7]));
    int cb = hh*32 + g4*4;
    f32x4 b0 = *(const f32x4*)(bias + cb);
    f32x4 b1 = *(const f32x4*)(bias + cb + 16);
    f32x4 f0 = *(const f32x4*)(fcw + cb);
    f32x4 f1 = *(const f32x4*)(fcw + cb + 16);
    float p = 0.f;
    #pragma unroll
    for (int g = 0; g < 4; ++g){
      p += fmaxf(aA[g]*inv + b0[g], 0.f) * f0[g];
      p += fmaxf(aB[g]*inv + b1[g], 0.f) * f1[g];
    }
    p += __shfl_xor(p, 16, 64);
    p += __shfl_xor(p, 32, 64);
    p += __shfl_xor(p, 1, 64);
    p += __shfl_xor(p, 2, 64);
    if (hh == 0 && g4 == 0){
      int nn = bt * 4 + n2;
      if (nn < N) out[nn] = 1.f / (1.f + __expf(-(p + fcb[0])));
    }
  }
}

extern "C" void kernel_launch(void* const* d_in, const int* in_sizes, int n_in,
                              void* d_out, int out_size, void* d_ws, size_t ws_size,
                              hipStream_t stream) {
  const float* x    = (const float*)d_in[0];
  const int*   ei   = (const int*)  d_in[1];
  const float* W    = (const float*)d_in[2];
  const float* attS = (const float*)d_in[3];
  const float* attD = (const float*)d_in[4];
  const float* bias = (const float*)d_in[5];
  const float* fcw  = (const float*)d_in[6];
  const float* fcb  = (const float*)d_in[7];

  int N = in_sizes[0] / 128;
  int E = in_sizes[1] / 2;
  const int* srcA = ei;
  const int* dstA = ei + E;

  char* ws = (char*)d_ws;
  size_t off = 0;
  auto alloc = [&](size_t bytes) -> void* {
    void* p = ws + off;
    off += (bytes + 255) & ~(size_t)255;
    return p;
  };
  uint4* xb4  = (uint4*)alloc((size_t)N * 256);
  float* aS   = (float*)alloc((size_t)N * 4 * 4);
  float* aD   = (float*)alloc((size_t)N * 4 * 4);
  int* deg    = (int*)alloc((size_t)N * 4);
  int* rowptr = (int*)alloc(((size_t)N + 1) * 4);
  int* cursor = (int*)alloc((size_t)N * 4);
  int* csr    = (int*)alloc((size_t)E * 4);
  int* bsum   = (int*)alloc(4096);
  unsigned short* WbfT = (unsigned short*)alloc(128 * 136 * 2);
  float* WS   = (float*)alloc(128 * 4 * 4);
  float* WD   = (float*)alloc(128 * 4 * 4);

  int n4 = (N + 3) / 4;
  k_init<<<(n4 + 255) / 256, 256, 0, stream>>>(W, attS, attD, WbfT, WS, WD,
                                               (int4*)deg, n4);
  k_cast<<<(N + 15) / 16, 256, 0, stream>>>(x, WS, WD, xb4, aS, aD, N);
  k_hist<<<(E + 255) / 256, 256, 0, stream>>>(dstA, E, deg);
  int nb = (N + 2047) / 2048;
  k_chunksum<<<nb, 256, 0, stream>>>(deg, N, bsum);
  k_scansums<<<1, 256, 0, stream>>>(bsum, nb);
  k_scanfinal<<<nb, 256, 0, stream>>>(deg, bsum, N, E, rowptr, cursor);
  k_scatter<<<(E + 255) / 256, 256, 0, stream>>>(srcA, dstA, E, cursor, csr);
  int nbatch = (N + 3) / 4;
  k_aggr2<<<768, 256, 0, stream>>>(xb4, aS, aD, rowptr, csr, bias, fcw, fcb,
                                   WbfT, (float*)d_out, N, nbatch);
}

// Round 9
// 366.650 us; speedup vs baseline: 1.7264x; 1.7264x over previous
//
#include <hip/hip_runtime.h>

typedef __attribute__((ext_vector_type(8))) short bf16x8;
typedef __attribute__((ext_vector_type(4))) float f32x4;

__device__ __forceinline__ unsigned short f2bf(float f){
  unsigned int u = __builtin_bit_cast(unsigned int, f);
  u += 0x7fffu + ((u >> 16) & 1u);          // RTN-even
  return (unsigned short)(u >> 16);
}
__device__ __forceinline__ float bf_lo(unsigned int v){
  return __builtin_bit_cast(float, v << 16);
}
__device__ __forceinline__ float bf_hi(unsigned int v){
  return __builtin_bit_cast(float, v & 0xffff0000u);
}
__device__ __forceinline__ float lrelu(float x){ return x > 0.f ? x : 0.2f * x; }

#define GLOAD_LDS16(g, l) \
  __builtin_amdgcn_global_load_lds((const __attribute__((address_space(1))) unsigned int*)(g), \
                                   (__attribute__((address_space(3))) unsigned int*)(l), 16, 0, 0)

// ---------------- Kernel I: zero deg + W (f32 [k][c]) -> bf16 W^T [c][136] ---
__global__ __launch_bounds__(256) void k_init(const float* __restrict__ W,
                                              unsigned short* __restrict__ WbfT,
                                              int4* __restrict__ deg4, int n4){
  int i = blockIdx.x * 256 + threadIdx.x;
  if (i < n4){ int4 z; z.x=0; z.y=0; z.z=0; z.w=0; deg4[i] = z; }
  if (i < 128*128){
    int c = i & 127, k = i >> 7;
    WbfT[c * 136 + k] = f2bf(W[k * 128 + c]);
  }
}

// ---------------- Kernel A: h = x@W (bf16 MFMA, async triple-buffered) ------
// 256 blocks x 4 waves. Wave = one 16-row slice, grid-stride. x staged via
// global_load_lds into 3 wave-private buffers; steady-state wait vmcnt(16)
// keeps 2 slices' loads in flight across compute. No barriers in the loop.
__global__ __launch_bounds__(256) void k_gemm(
    const float* __restrict__ x, const unsigned short* __restrict__ WbfT,
    const float* __restrict__ attS, const float* __restrict__ attD,
    unsigned short* __restrict__ h, float* __restrict__ aS, float* __restrict__ aD,
    int N, int nslices)
{
  __shared__ unsigned short Wt[128][136];     // 34816 B
  __shared__ float xbuf[4][3][16*128];        // 4 waves x 3 bufs x 8KB = 96KB
  int tid = threadIdx.x;

  const char* wsrc = (const char*)WbfT;
  #pragma unroll
  for (int it = 0; it < 9; ++it){
    int i = it * 256 + tid;
    if (i < 2176) GLOAD_LDS16(wsrc + (size_t)i * 16, ((char*)Wt) + i * 16);
  }
  __syncthreads();   // once; loop below has no block-wide sync

  int wv = tid >> 6, lane = tid & 63;
  int lrow = lane & 15, lgrp = lane >> 4;

  int slice  = (int)blockIdx.x * 4 + wv;
  int stride = (int)gridDim.x * 4;

  // stage slice s into buf b (8 x global_load_lds, 1KB each, wave-uniform dest)
  auto STAGE = [&](int s, int b){
    if (s >= nslices) s = nslices - 1;
    char* dst0 = (char*)&xbuf[wv][b][0];
    #pragma unroll
    for (int k = 0; k < 8; ++k){
      int c = k * 64 + lane;          // LDS chunk this lane fills
      int r = c >> 5, j = c & 31;     // row, chunk-in-row
      int gr = s * 16 + r; if (gr >= N) gr = N - 1;
      const char* src = (const char*)(x + (size_t)gr * 128) + ((j ^ (r & 7)) << 4);
      GLOAD_LDS16(src, dst0 + k * 1024);
    }
  };

  STAGE(slice, 0);
  STAGE(slice + stride, 1);
  int bi = 0;

  for (int s = slice; s < nslices; s += stride){
    STAGE(s + 2 * stride, (bi + 2) % 3);
    asm volatile("s_waitcnt vmcnt(16)" ::: "memory");   // buf bi complete

    // A-fragments from LDS (swizzled chunks), convert to bf16
    const f32x4* xb = (const f32x4*)&xbuf[wv][bi][0];
    bf16x8 af[4];
    #pragma unroll
    for (int kt = 0; kt < 4; ++kt){
      int j0 = kt * 8 + lgrp * 2;
      f32x4 lo = xb[lrow * 32 + ( j0      ^ (lrow & 7))];
      f32x4 hi = xb[lrow * 32 + ((j0 + 1) ^ (lrow & 7))];
      bf16x8 a;
      #pragma unroll
      for (int j = 0; j < 4; ++j){
        a[j]   = (short)f2bf(lo[j]);
        a[4+j] = (short)f2bf(hi[j]);
      }
      af[kt] = a;
    }

    f32x4 acc[8];
    #pragma unroll
    for (int ct = 0; ct < 8; ++ct){ acc[ct][0]=0.f; acc[ct][1]=0.f; acc[ct][2]=0.f; acc[ct][3]=0.f; }
    #pragma unroll
    for (int kt = 0; kt < 4; ++kt){
      #pragma unroll
      for (int ct = 0; ct < 8; ++ct){
        bf16x8 bw = *(const bf16x8*)&Wt[ct*16 + lrow][kt*32 + lgrp*8];
        acc[ct] = __builtin_amdgcn_mfma_f32_16x16x32_bf16(bw, af[kt], acc[ct], 0, 0, 0);
      }
    }

    // epilogue: lane owns row = s*16+lrow, cols ct*16 + lgrp*4 + (0..3)
    int row = s * 16 + lrow;
    float ps[4] = {0.f,0.f,0.f,0.f}, pd[4] = {0.f,0.f,0.f,0.f};
    #pragma unroll
    for (int ct = 0; ct < 8; ++ct){
      int hh = ct >> 1;
      f32x4 s4 = *(const f32x4*)(attS + ct*16 + lgrp*4);
      f32x4 d4 = *(const f32x4*)(attD + ct*16 + lgrp*4);
      #pragma unroll
      for (int g = 0; g < 4; ++g){
        ps[hh] += acc[ct][g] * s4[g];
        pd[hh] += acc[ct][g] * d4[g];
      }
    }
    #pragma unroll
    for (int hh = 0; hh < 4; ++hh){
      ps[hh] += __shfl_xor(ps[hh], 16, 64);
      ps[hh] += __shfl_xor(ps[hh], 32, 64);
      pd[hh] += __shfl_xor(pd[hh], 16, 64);
      pd[hh] += __shfl_xor(pd[hh], 32, 64);
    }
    if (lgrp == 0 && row < N){
      f32x4 vs, vd;
      #pragma unroll
      for (int hh = 0; hh < 4; ++hh){ vs[hh] = ps[hh]; vd[hh] = pd[hh]; }
      *(f32x4*)(aS + (size_t)row * 4) = vs;
      *(f32x4*)(aD + (size_t)row * 4) = vd;
    }
    if (row < N){
      unsigned short* hp = h + (size_t)row * 128 + lgrp * 4;
      #pragma unroll
      for (int ct = 0; ct < 8; ++ct){
        unsigned int u0 = (unsigned int)f2bf(acc[ct][0])
                        | ((unsigned int)f2bf(acc[ct][1]) << 16);
        unsigned int u1 = (unsigned int)f2bf(acc[ct][2])
                        | ((unsigned int)f2bf(acc[ct][3]) << 16);
        uint2 u; u.x = u0; u.y = u1;
        *(uint2*)(hp + ct * 16) = u;
      }
    }
    bi = (bi + 1) % 3;
  }
}

// ---------------- CSR build ----------------
__global__ __launch_bounds__(256) void k_hist(const int* __restrict__ dst, int E,
                                              int* __restrict__ deg){
  int e = blockIdx.x * 256 + threadIdx.x;
  if (e < E) atomicAdd(&deg[dst[e]], 1);
}

__global__ __launch_bounds__(256) void k_chunksum(const int* __restrict__ deg, int N,
                                                  int* __restrict__ bsum){
  __shared__ int sm[256];
  int tid = threadIdx.x;
  int base = blockIdx.x * 2048 + tid * 8;
  int s = 0;
  #pragma unroll
  for (int j = 0; j < 8; ++j) s += (base + j < N) ? deg[base + j] : 0;
  sm[tid] = s; __syncthreads();
  for (int off = 128; off > 0; off >>= 1){
    if (tid < off) sm[tid] += sm[tid + off];
    __syncthreads();
  }
  if (tid == 0) bsum[blockIdx.x] = sm[0];
}

__global__ __launch_bounds__(256) void k_scansums(int* __restrict__ bsum, int nb){
  __shared__ int sm[256];
  int tid = threadIdx.x;
  int carry = 0;
  for (int base = 0; base < nb; base += 256){
    int v = (base + tid < nb) ? bsum[base + tid] : 0;
    sm[tid] = v; __syncthreads();
    for (int off = 1; off < 256; off <<= 1){
      int t = (tid >= off) ? sm[tid - off] : 0;
      __syncthreads();
      sm[tid] += t;
      __syncthreads();
    }
    int incl = sm[tid];
    int total = sm[255];
    __syncthreads();
    if (base + tid < nb) bsum[base + tid] = carry + incl - v;
    carry += total;
  }
}

__global__ __launch_bounds__(256) void k_scanfinal(const int* __restrict__ deg,
    const int* __restrict__ bsum, int N, int E,
    int* __restrict__ rowptr, int* __restrict__ cursor){
  __shared__ int sm[256];
  int tid = threadIdx.x;
  int base = blockIdx.x * 2048 + tid * 8;
  int v[8];
  #pragma unroll
  for (int j = 0; j < 8; ++j) v[j] = (base + j < N) ? deg[base + j] : 0;
  int t = 0;
  #pragma unroll
  for (int j = 0; j < 8; ++j){ int x_ = v[j]; v[j] = t; t += x_; }
  sm[tid] = t; __syncthreads();
  for (int off = 1; off < 256; off <<= 1){
    int u = (tid >= off) ? sm[tid - off] : 0;
    __syncthreads();
    sm[tid] += u;
    __syncthreads();
  }
  int excl = sm[tid] - t;
  int off0 = bsum[blockIdx.x] + excl;
  #pragma unroll
  for (int j = 0; j < 8; ++j){
    if (base + j < N){
      int val = off0 + v[j];
      rowptr[base + j] = val;
      cursor[base + j] = val;
    }
  }
  if (blockIdx.x == 0 && tid == 0) rowptr[N] = E;
}

// ------- Kernel S: scatter src into CSR slot + precompute edge weights ------
// wexp[p*4+h] = exp(lrelu(aS[src][h] + aD[dst][h])) in CSR order.
__global__ __launch_bounds__(256) void k_scatter(const int* __restrict__ src,
    const int* __restrict__ dst, int E, int* __restrict__ cursor,
    const float* __restrict__ aS, const float* __restrict__ aD,
    int* __restrict__ csr, float* __restrict__ wexp){
  int e = blockIdx.x * 256 + threadIdx.x;
  if (e < E){
    int s = src[e], d = dst[e];
    int p = atomicAdd(&cursor[d], 1);
    csr[p] = s;
    f32x4 as = *(const f32x4*)(aS + (size_t)s * 4);
    f32x4 ad = *(const f32x4*)(aD + (size_t)d * 4);
    f32x4 w;
    #pragma unroll
    for (int hh = 0; hh < 4; ++hh) w[hh] = __expf(lrelu(as[hh] + ad[hh]));
    *(f32x4*)(wexp + (size_t)p * 4) = w;
  }
}

// ---------------- Kernel C: gather with precomputed weights + fc head -------
// 4 nodes per wave; 16 lanes per node; lane owns 8 channels (4 dwords).
// Inner loop: NO exp, NO aS gather — just wexp (CSR-sequential) + h row.
__global__ __launch_bounds__(256) void k_aggr(
    const uint4* __restrict__ h4, const float* __restrict__ aS,
    const float* __restrict__ aD, const int* __restrict__ rowptr,
    const int* __restrict__ csr, const float* __restrict__ wexp,
    const float* __restrict__ bias, const float* __restrict__ fcw,
    const float* __restrict__ fcb, float* __restrict__ out, int N)
{
  int lane = threadIdx.x & 63;
  int l16  = lane & 15;
  int node = ((int)blockIdx.x * 256 + (int)threadIdx.x) >> 4;
  if (node >= N) return;
  int head = l16 >> 2;

  float wself = __expf(lrelu(aS[node * 4 + head] + aD[node * 4 + head]));
  float wsum  = wself;

  float acc[8];
  {
    uint4 hv = h4[node * 16 + l16];
    acc[0] = wself * bf_lo(hv.x);  acc[1] = wself * bf_hi(hv.x);
    acc[2] = wself * bf_lo(hv.y);  acc[3] = wself * bf_hi(hv.y);
    acc[4] = wself * bf_lo(hv.z);  acc[5] = wself * bf_hi(hv.z);
    acc[6] = wself * bf_lo(hv.w);  acc[7] = wself * bf_hi(hv.w);
  }

  int rb = rowptr[node], re = rowptr[node + 1];
  for (int j = rb; j < re; j += 4){
    int i1 = (j + 1 < re) ? j + 1 : j;
    int i2 = (j + 2 < re) ? j + 2 : j;
    int i3 = (j + 3 < re) ? j + 3 : j;
    int s0 = csr[j], s1 = csr[i1], s2 = csr[i2], s3 = csr[i3];
    float m1 = (j + 1 < re) ? 1.f : 0.f;
    float m2 = (j + 2 < re) ? 1.f : 0.f;
    float m3 = (j + 3 < re) ? 1.f : 0.f;
    float w0 = wexp[(size_t)j  * 4 + head];
    float w1 = wexp[(size_t)i1 * 4 + head] * m1;
    float w2 = wexp[(size_t)i2 * 4 + head] * m2;
    float w3 = wexp[(size_t)i3 * 4 + head] * m3;
    uint4 v0 = h4[(size_t)s0 * 16 + l16];
    uint4 v1 = h4[(size_t)s1 * 16 + l16];
    uint4 v2 = h4[(size_t)s2 * 16 + l16];
    uint4 v3 = h4[(size_t)s3 * 16 + l16];
    wsum += w0 + w1 + w2 + w3;
    acc[0] += w0*bf_lo(v0.x) + w1*bf_lo(v1.x) + w2*bf_lo(v2.x) + w3*bf_lo(v3.x);
    acc[1] += w0*bf_hi(v0.x) + w1*bf_hi(v1.x) + w2*bf_hi(v2.x) + w3*bf_hi(v3.x);
    acc[2] += w0*bf_lo(v0.y) + w1*bf_lo(v1.y) + w2*bf_lo(v2.y) + w3*bf_lo(v3.y);
    acc[3] += w0*bf_hi(v0.y) + w1*bf_hi(v1.y) + w2*bf_hi(v2.y) + w3*bf_hi(v3.y);
    acc[4] += w0*bf_lo(v0.z) + w1*bf_lo(v1.z) + w2*bf_lo(v2.z) + w3*bf_lo(v3.z);
    acc[5] += w0*bf_hi(v0.z) + w1*bf_hi(v1.z) + w2*bf_hi(v2.z) + w3*bf_hi(v3.z);
    acc[6] += w0*bf_lo(v0.w) + w1*bf_lo(v1.w) + w2*bf_lo(v2.w) + w3*bf_lo(v3.w);
    acc[7] += w0*bf_hi(v0.w) + w1*bf_hi(v1.w) + w2*bf_hi(v2.w) + w3*bf_hi(v3.w);
  }

  float inv = 1.f / wsum;
  const float* bp = bias + l16 * 8;
  const float* fp = fcw  + l16 * 8;
  f32x4 b0 = *(const f32x4*)bp,      b1 = *(const f32x4*)(bp + 4);
  f32x4 f0 = *(const f32x4*)fp,      f1 = *(const f32x4*)(fp + 4);
  float p = 0.f;
  p += fmaxf(acc[0]*inv + b0[0], 0.f) * f0[0];
  p += fmaxf(acc[1]*inv + b0[1], 0.f) * f0[1];
  p += fmaxf(acc[2]*inv + b0[2], 0.f) * f0[2];
  p += fmaxf(acc[3]*inv + b0[3], 0.f) * f0[3];
  p += fmaxf(acc[4]*inv + b1[0], 0.f) * f1[0];
  p += fmaxf(acc[5]*inv + b1[1], 0.f) * f1[1];
  p += fmaxf(acc[6]*inv + b1[2], 0.f) * f1[2];
  p += fmaxf(acc[7]*inv + b1[3], 0.f) * f1[3];
  #pragma unroll
  for (int m = 1; m < 16; m <<= 1) p += __shfl_xor(p, m, 64);
  if (l16 == 0) out[node] = 1.f / (1.f + __expf(-(p + fcb[0])));
}

extern "C" void kernel_launch(void* const* d_in, const int* in_sizes, int n_in,
                              void* d_out, int out_size, void* d_ws, size_t ws_size,
                              hipStream_t stream) {
  const float* x    = (const float*)d_in[0];
  const int*   ei   = (const int*)  d_in[1];
  const float* W    = (const float*)d_in[2];
  const float* attS = (const float*)d_in[3];
  const float* attD = (const float*)d_in[4];
  const float* bias = (const float*)d_in[5];
  const float* fcw  = (const float*)d_in[6];
  const float* fcb  = (const float*)d_in[7];

  int N = in_sizes[0] / 128;
  int E = in_sizes[1] / 2;
  const int* srcA = ei;
  const int* dstA = ei + E;

  char* ws = (char*)d_ws;
  size_t off = 0;
  auto alloc = [&](size_t bytes) -> void* {
    void* p = ws + off;
    off += (bytes + 255) & ~(size_t)255;
    return p;
  };
  unsigned short* h  = (unsigned short*)alloc((size_t)N * 128 * 2);
  float* aS   = (float*)alloc((size_t)N * 4 * 4);
  float* aD   = (float*)alloc((size_t)N * 4 * 4);
  int* deg    = (int*)alloc((size_t)N * 4);
  int* rowptr = (int*)alloc(((size_t)N + 1) * 4);
  int* cursor = (int*)alloc((size_t)N * 4);
  int* csr    = (int*)alloc((size_t)E * 4);
  float* wexp = (float*)alloc((size_t)E * 4 * 4);
  int* bsum   = (int*)alloc(4096);
  unsigned short* WbfT = (unsigned short*)alloc(128 * 136 * 2);

  int n4 = (N + 3) / 4;
  int ninit = (n4 > 16384) ? n4 : 16384;
  k_init<<<(ninit + 255) / 256, 256, 0, stream>>>(W, WbfT, (int4*)deg, n4);
  int nslices = (N + 15) / 16;
  k_gemm<<<256, 256, 0, stream>>>(x, WbfT, attS, attD, h, aS, aD, N, nslices);
  k_hist<<<(E + 255) / 256, 256, 0, stream>>>(dstA, E, deg);
  int nb = (N + 2047) / 2048;
  k_chunksum<<<nb, 256, 0, stream>>>(deg, N, bsum);
  k_scansums<<<1, 256, 0, stream>>>(bsum, nb);
  k_scanfinal<<<nb, 256, 0, stream>>>(deg, bsum, N, E, rowptr, cursor);
  k_scatter<<<(E + 255) / 256, 256, 0, stream>>>(srcA, dstA, E, cursor, aS, aD,
                                                 csr, wexp);
  k_aggr<<<(N + 15) / 16, 256, 0, stream>>>((const uint4*)h, aS, aD, rowptr, csr,
                                            wexp, bias, fcw, fcb, (float*)d_out, N);
}